// Round 1
// baseline (1036.958 us; speedup 1.0000x reference)
//
#include <hip/hip_runtime.h>
#include <hip/hip_bf16.h>
#include <math.h>

#define NEG_MASK -999999.0f

constexpr int BB = 64, PP = 512, HH = 512, DD = 512;

// ---------------- sim = pre @ hyp^T  (per batch) ----------------
// 64x64 tile per block, BK=16, 256 threads, 4x4 microtile/thread.
__global__ __launch_bounds__(256) void sim_gemm(const float* __restrict__ pre,
                                                const float* __restrict__ hyp,
                                                float* __restrict__ sim) {
  const int b = blockIdx.z;
  const int pRow0 = blockIdx.y * 64;
  const int hCol0 = blockIdx.x * 64;
  const float* A = pre + (size_t)b * PP * DD;
  const float* Bm = hyp + (size_t)b * HH * DD;
  float* S = sim + (size_t)b * PP * HH;

  __shared__ float As[16][68];
  __shared__ float Bs[16][68];

  const int tid = threadIdx.x;
  const int lr = tid >> 2;          // 0..63 tile row
  const int lk = (tid & 3) << 2;    // 0,4,8,12 k offset
  const int tx = tid & 15, ty = tid >> 4;

  float acc[4][4] = {};

  for (int kk = 0; kk < DD; kk += 16) {
    float4 av = *reinterpret_cast<const float4*>(A + (size_t)(pRow0 + lr) * DD + kk + lk);
    float4 bv = *reinterpret_cast<const float4*>(Bm + (size_t)(hCol0 + lr) * DD + kk + lk);
    __syncthreads();
    As[lk + 0][lr] = av.x; As[lk + 1][lr] = av.y; As[lk + 2][lr] = av.z; As[lk + 3][lr] = av.w;
    Bs[lk + 0][lr] = bv.x; Bs[lk + 1][lr] = bv.y; Bs[lk + 2][lr] = bv.z; Bs[lk + 3][lr] = bv.w;
    __syncthreads();
#pragma unroll
    for (int k = 0; k < 16; ++k) {
      float4 a4 = *reinterpret_cast<const float4*>(&As[k][ty * 4]);
      float4 b4 = *reinterpret_cast<const float4*>(&Bs[k][tx * 4]);
      float ar[4] = {a4.x, a4.y, a4.z, a4.w};
      float br[4] = {b4.x, b4.y, b4.z, b4.w};
#pragma unroll
      for (int i = 0; i < 4; ++i)
#pragma unroll
        for (int j = 0; j < 4; ++j)
          acc[i][j] = fmaf(ar[i], br[j], acc[i][j]);
    }
  }
#pragma unroll
  for (int i = 0; i < 4; ++i) {
    float4 o = {acc[i][0], acc[i][1], acc[i][2], acc[i][3]};
    *reinterpret_cast<float4*>(S + (size_t)(pRow0 + ty * 4 + i) * HH + hCol0 + tx * 4) = o;
  }
}

// ---------------- softmax stats over h (axis=2), per (b,p) row ----------------
__global__ __launch_bounds__(256) void stats_rows(const float* __restrict__ sim,
                                                  const int* __restrict__ pmask,
                                                  float* __restrict__ maxA,
                                                  float* __restrict__ sumA) {
  const int row = blockIdx.x;               // b*PP + p
  const float* s = sim + (size_t)row * HH;
  const float c = (pmask[row] == 0) ? NEG_MASK : 0.f;
  const int t = threadIdx.x;

  __shared__ float red[256];

  float m = -3.4e38f;
  for (int i = t; i < HH; i += 256) m = fmaxf(m, s[i] + c);
  red[t] = m;
  __syncthreads();
  for (int o = 128; o; o >>= 1) {
    if (t < o) red[t] = fmaxf(red[t], red[t + o]);
    __syncthreads();
  }
  m = red[0];
  __syncthreads();

  float sum = 0.f;
  for (int i = t; i < HH; i += 256) sum += __expf((s[i] + c) - m);
  red[t] = sum;
  __syncthreads();
  for (int o = 128; o; o >>= 1) {
    if (t < o) red[t] += red[t + o];
    __syncthreads();
  }
  if (t == 0) {
    maxA[row] = m;
    sumA[row] = red[0];
  }
}

// ---------------- softmax stats over p (axis=1), per (b,h) column ----------------
__global__ __launch_bounds__(256) void stats_cols(const float* __restrict__ sim,
                                                  const int* __restrict__ hmask,
                                                  float* __restrict__ maxB,
                                                  float* __restrict__ sumB) {
  const int b = blockIdx.y;
  const int h = blockIdx.x * 256 + threadIdx.x;
  const float* s = sim + (size_t)b * PP * HH + h;
  const float c = (hmask[b * HH + h] == 0) ? NEG_MASK : 0.f;

  float m = -3.4e38f;
  for (int p = 0; p < PP; ++p) m = fmaxf(m, s[(size_t)p * HH] + c);
  float sum = 0.f;
  for (int p = 0; p < PP; ++p) sum += __expf((s[(size_t)p * HH] + c) - m);
  maxB[b * HH + h] = m;
  sumB[b * HH + h] = sum;
}

// ---------------- attended_premises[b,p,d] = softmax_h(sim) @ hyp ----------------
__global__ __launch_bounds__(256) void att_a(const float* __restrict__ sim,
                                             const float* __restrict__ hyp,
                                             const int* __restrict__ pmask,
                                             const float* __restrict__ maxA,
                                             const float* __restrict__ sumA,
                                             float* __restrict__ out) {
  const int b = blockIdx.z;
  const int pRow0 = blockIdx.y * 64;
  const int dCol0 = blockIdx.x * 64;
  const float* S = sim + (size_t)b * PP * HH;
  const float* V = hyp + (size_t)b * HH * DD;
  float* O = out + (size_t)b * PP * DD;

  __shared__ float Ws[16][68];
  __shared__ float Vs[16][68];

  const int tid = threadIdx.x;
  const int lr = tid >> 2;          // p row 0..63 (A-tile)
  const int lk = (tid & 3) << 2;    // h 0,4,8,12 (A-tile)
  const int bk = tid >> 4;          // h row 0..15 (B-tile)
  const int bc = (tid & 15) << 2;   // d col (B-tile)
  const int tx = tid & 15, ty = tid >> 4;

  const int prow = b * PP + pRow0 + lr;
  const float c = (pmask[prow] == 0) ? NEG_MASK : 0.f;
  const float mrow = maxA[prow];

  float acc[4][4] = {};

  for (int kk = 0; kk < HH; kk += 16) {
    float4 sv = *reinterpret_cast<const float4*>(S + (size_t)(pRow0 + lr) * HH + kk + lk);
    float4 vv = *reinterpret_cast<const float4*>(V + (size_t)(kk + bk) * DD + dCol0 + bc);
    __syncthreads();
    Ws[lk + 0][lr] = __expf((sv.x + c) - mrow);
    Ws[lk + 1][lr] = __expf((sv.y + c) - mrow);
    Ws[lk + 2][lr] = __expf((sv.z + c) - mrow);
    Ws[lk + 3][lr] = __expf((sv.w + c) - mrow);
    *reinterpret_cast<float4*>(&Vs[bk][bc]) = vv;
    __syncthreads();
#pragma unroll
    for (int k = 0; k < 16; ++k) {
      float4 a4 = *reinterpret_cast<const float4*>(&Ws[k][ty * 4]);
      float4 b4 = *reinterpret_cast<const float4*>(&Vs[k][tx * 4]);
      float ar[4] = {a4.x, a4.y, a4.z, a4.w};
      float br[4] = {b4.x, b4.y, b4.z, b4.w};
#pragma unroll
      for (int i = 0; i < 4; ++i)
#pragma unroll
        for (int j = 0; j < 4; ++j)
          acc[i][j] = fmaf(ar[i], br[j], acc[i][j]);
    }
  }
#pragma unroll
  for (int i = 0; i < 4; ++i) {
    const float inv = 1.f / sumA[b * PP + pRow0 + ty * 4 + i];
    float4 o = {acc[i][0] * inv, acc[i][1] * inv, acc[i][2] * inv, acc[i][3] * inv};
    *reinterpret_cast<float4*>(O + (size_t)(pRow0 + ty * 4 + i) * DD + dCol0 + tx * 4) = o;
  }
}

// ---------------- attended_hypothesis[b,h,d] = softmax_p(sim)^T @ pre ----------------
__global__ __launch_bounds__(256) void att_b(const float* __restrict__ sim,
                                             const float* __restrict__ pre,
                                             const int* __restrict__ hmask,
                                             const float* __restrict__ maxB,
                                             const float* __restrict__ sumB,
                                             float* __restrict__ out) {
  const int b = blockIdx.z;
  const int hRow0 = blockIdx.y * 64;
  const int dCol0 = blockIdx.x * 64;
  const float* S = sim + (size_t)b * PP * HH;
  const float* U = pre + (size_t)b * PP * DD;
  float* O = out + (size_t)b * HH * DD;

  __shared__ float Ws[16][68];
  __shared__ float Us[16][68];

  const int tid = threadIdx.x;
  const int ak = tid >> 4;           // p row 0..15 (A-tile, k dim)
  const int ar4 = (tid & 15) << 2;   // h col (A-tile)
  const int tx = tid & 15, ty = tid >> 4;

  const int hbase = b * HH + hRow0 + ar4;
  float cj[4], mj[4];
#pragma unroll
  for (int j = 0; j < 4; ++j) {
    cj[j] = (hmask[hbase + j] == 0) ? NEG_MASK : 0.f;
    mj[j] = maxB[hbase + j];
  }

  float acc[4][4] = {};

  for (int kk = 0; kk < PP; kk += 16) {
    float4 sv = *reinterpret_cast<const float4*>(S + (size_t)(kk + ak) * HH + hRow0 + ar4);
    float4 uv = *reinterpret_cast<const float4*>(U + (size_t)(kk + ak) * DD + dCol0 + ar4);
    __syncthreads();
    float4 w;
    w.x = __expf((sv.x + cj[0]) - mj[0]);
    w.y = __expf((sv.y + cj[1]) - mj[1]);
    w.z = __expf((sv.z + cj[2]) - mj[2]);
    w.w = __expf((sv.w + cj[3]) - mj[3]);
    *reinterpret_cast<float4*>(&Ws[ak][ar4]) = w;
    *reinterpret_cast<float4*>(&Us[ak][ar4]) = uv;
    __syncthreads();
#pragma unroll
    for (int k = 0; k < 16; ++k) {
      float4 a4 = *reinterpret_cast<const float4*>(&Ws[k][ty * 4]);
      float4 b4 = *reinterpret_cast<const float4*>(&Us[k][tx * 4]);
      float ar[4] = {a4.x, a4.y, a4.z, a4.w};
      float br[4] = {b4.x, b4.y, b4.z, b4.w};
#pragma unroll
      for (int i = 0; i < 4; ++i)
#pragma unroll
        for (int j = 0; j < 4; ++j)
          acc[i][j] = fmaf(ar[i], br[j], acc[i][j]);
    }
  }
#pragma unroll
  for (int i = 0; i < 4; ++i) {
    const float inv = 1.f / sumB[b * HH + hRow0 + ty * 4 + i];
    float4 o = {acc[i][0] * inv, acc[i][1] * inv, acc[i][2] * inv, acc[i][3] * inv};
    *reinterpret_cast<float4*>(O + (size_t)(hRow0 + ty * 4 + i) * DD + dCol0 + tx * 4) = o;
  }
}

extern "C" void kernel_launch(void* const* d_in, const int* in_sizes, int n_in,
                              void* d_out, int out_size, void* d_ws, size_t ws_size,
                              hipStream_t stream) {
  const float* pre = (const float*)d_in[0];
  const int* pmask = (const int*)d_in[1];
  const float* hyp = (const float*)d_in[2];
  const int* hmask = (const int*)d_in[3];

  float* out0 = (float*)d_out;                       // attended_premises  [B,P,D]
  float* out1 = out0 + (size_t)BB * PP * DD;         // attended_hypothesis [B,H,D]

  float* sim  = (float*)d_ws;                        // [B,P,H]
  float* maxA = sim + (size_t)BB * PP * HH;          // [B,P]
  float* sumA = maxA + BB * PP;
  float* maxB = sumA + BB * PP;                      // [B,H]
  float* sumB = maxB + BB * HH;

  sim_gemm<<<dim3(HH / 64, PP / 64, BB), 256, 0, stream>>>(pre, hyp, sim);
  stats_rows<<<dim3(BB * PP), 256, 0, stream>>>(sim, pmask, maxA, sumA);
  stats_cols<<<dim3(HH / 256, BB), 256, 0, stream>>>(sim, hmask, maxB, sumB);
  att_a<<<dim3(DD / 64, PP / 64, BB), 256, 0, stream>>>(sim, hyp, pmask, maxA, sumA, out0);
  att_b<<<dim3(DD / 64, HH / 64, BB), 256, 0, stream>>>(sim, pre, hmask, maxB, sumB, out1);
}

// Round 2
// 437.974 us; speedup vs baseline: 2.3676x; 2.3676x over previous
//
#include <hip/hip_runtime.h>
#include <hip/hip_bf16.h>
#include <math.h>

#define NEG_MASK -999999.0f

constexpr int BB = 64, PP = 512, HH = 512, DD = 512;

typedef __bf16 bfrag __attribute__((ext_vector_type(8)));   // MFMA A/B operand (4 VGPRs)
typedef __bf16 bf4   __attribute__((ext_vector_type(4)));   // 8B LDS write chunk
typedef float  f32x4 __attribute__((ext_vector_type(4)));   // MFMA C/D + global loads

#define MFMA(a, b, c) __builtin_amdgcn_mfma_f32_16x16x32_bf16(a, b, c, 0, 0, 0)

// XOR swizzle for [128 rows][32 bf16] LDS tiles (row stride 64B). Applied
// identically on write and read, so layout is consistent; spreads the
// b128 fragment reads (16 rows x 4 k-chunks) across bank slots.
__device__ __forceinline__ int swz(int row, int kb) {
  return (row * 64 + kb) ^ ((row & 7) << 4);
}

// ================= sim = pre @ hyp^T, 2-term bf16 split (3 MFMAs) =================
__global__ __launch_bounds__(256, 2) void sim_mfma(const float* __restrict__ pre,
                                                   const float* __restrict__ hyp,
                                                   float* __restrict__ sim) {
  const int b = blockIdx.z;
  const int p0 = blockIdx.y * 128, h0 = blockIdx.x * 128;
  const float* A  = pre + (size_t)b * PP * DD;
  const float* Bm = hyp + (size_t)b * HH * DD;

  __shared__ char sAh[128 * 64], sAl[128 * 64], sBh[128 * 64], sBl[128 * 64];

  const int t = threadIdx.x;
  const int r = t >> 1, kh = t & 1;          // staging: row, k-half
  const int lane = t & 63, wid = t >> 6;
  const int l15 = lane & 15, l4 = lane >> 4;
  const int wr = (wid >> 1) * 64, wc = (wid & 1) * 64;

  f32x4 acc[4][4] = {};

  const float* pA = A  + (size_t)(p0 + r) * DD + kh * 16;
  const float* pB = Bm + (size_t)(h0 + r) * DD + kh * 16;

  for (int kk = 0; kk < DD; kk += 32) {
    f32x4 ra[4], rb[4];
#pragma unroll
    for (int c = 0; c < 4; ++c) {
      ra[c] = *reinterpret_cast<const f32x4*>(pA + kk + c * 4);
      rb[c] = *reinterpret_cast<const f32x4*>(pB + kk + c * 4);
    }
    __syncthreads();   // previous iteration's fragment reads done
#pragma unroll
    for (int c = 0; c < 4; ++c) {
      const int kb = kh * 32 + c * 8;
      bf4 ah, al, bh, bl;
#pragma unroll
      for (int e = 0; e < 4; ++e) {
        float fa = ra[c][e], fb = rb[c][e];
        __bf16 ha = (__bf16)fa, hb = (__bf16)fb;
        ah[e] = ha; al[e] = (__bf16)(fa - (float)ha);
        bh[e] = hb; bl[e] = (__bf16)(fb - (float)hb);
      }
      *reinterpret_cast<bf4*>(sAh + swz(r, kb)) = ah;
      *reinterpret_cast<bf4*>(sAl + swz(r, kb)) = al;
      *reinterpret_cast<bf4*>(sBh + swz(r, kb)) = bh;
      *reinterpret_cast<bf4*>(sBl + swz(r, kb)) = bl;
    }
    __syncthreads();

    bfrag Ah[4], Al[4], Bh[4], Bl[4];
#pragma unroll
    for (int i = 0; i < 4; ++i) {
      Ah[i] = *reinterpret_cast<const bfrag*>(sAh + swz(wr + i * 16 + l15, l4 * 16));
      Al[i] = *reinterpret_cast<const bfrag*>(sAl + swz(wr + i * 16 + l15, l4 * 16));
      Bh[i] = *reinterpret_cast<const bfrag*>(sBh + swz(wc + i * 16 + l15, l4 * 16));
      Bl[i] = *reinterpret_cast<const bfrag*>(sBl + swz(wc + i * 16 + l15, l4 * 16));
    }
#pragma unroll
    for (int i = 0; i < 4; ++i)
#pragma unroll
      for (int j = 0; j < 4; ++j) {
        acc[i][j] = MFMA(Ah[i], Bh[j], acc[i][j]);
        acc[i][j] = MFMA(Ah[i], Bl[j], acc[i][j]);
        acc[i][j] = MFMA(Al[i], Bh[j], acc[i][j]);
      }
  }

  float* S = sim + (size_t)b * PP * HH;
#pragma unroll
  for (int i = 0; i < 4; ++i)
#pragma unroll
    for (int j = 0; j < 4; ++j)
#pragma unroll
      for (int rr = 0; rr < 4; ++rr)
        S[(size_t)(p0 + wr + i * 16 + l4 * 4 + rr) * HH + h0 + wc + j * 16 + l15] =
            acc[i][j][rr];
}

// ================= stats over h (axis=2): one wave per row =================
__global__ __launch_bounds__(256) void stats_rows(const float* __restrict__ sim,
                                                  const int* __restrict__ pmask,
                                                  float* __restrict__ maxA,
                                                  float* __restrict__ sumA) {
  const int wid = threadIdx.x >> 6, lane = threadIdx.x & 63;
  const int row = blockIdx.x * 4 + wid;          // b*PP + p
  const float* s = sim + (size_t)row * HH + lane * 8;
  const float c = (pmask[row] == 0) ? NEG_MASK : 0.f;

  f32x4 v0 = *reinterpret_cast<const f32x4*>(s);
  f32x4 v1 = *reinterpret_cast<const f32x4*>(s + 4);
  float tv[8] = {v0[0] + c, v0[1] + c, v0[2] + c, v0[3] + c,
                 v1[0] + c, v1[1] + c, v1[2] + c, v1[3] + c};
  float m = tv[0];
#pragma unroll
  for (int e = 1; e < 8; ++e) m = fmaxf(m, tv[e]);
#pragma unroll
  for (int o = 1; o < 64; o <<= 1) m = fmaxf(m, __shfl_xor(m, o, 64));
  float sum = 0.f;
#pragma unroll
  for (int e = 0; e < 8; ++e) sum += __expf(tv[e] - m);
#pragma unroll
  for (int o = 1; o < 64; o <<= 1) sum += __shfl_xor(sum, o, 64);
  if (lane == 0) { maxA[row] = m; sumA[row] = sum; }
}

// ================= stats over p (axis=1): 64 h per block, 4 p-segments =================
__global__ __launch_bounds__(256) void stats_cols(const float* __restrict__ sim,
                                                  const int* __restrict__ hmask,
                                                  float* __restrict__ maxB,
                                                  float* __restrict__ sumB) {
  const int b = blockIdx.y;
  const int th = threadIdx.x & 63, seg = threadIdx.x >> 6;
  const int h = blockIdx.x * 64 + th;
  const float* s = sim + (size_t)b * PP * HH + h;
  const float c = (hmask[b * HH + h] == 0) ? NEG_MASK : 0.f;

  __shared__ float red[4][64];

  float m = -3.4e38f;
  for (int p = seg * 128; p < seg * 128 + 128; ++p)
    m = fmaxf(m, s[(size_t)p * HH] + c);
  red[seg][th] = m;
  __syncthreads();
  m = fmaxf(fmaxf(red[0][th], red[1][th]), fmaxf(red[2][th], red[3][th]));

  float sum = 0.f;
  for (int p = seg * 128; p < seg * 128 + 128; ++p)
    sum += __expf((s[(size_t)p * HH] + c) - m);
  __syncthreads();
  red[seg][th] = sum;
  __syncthreads();
  if (seg == 0) {
    maxB[b * HH + h] = m;
    sumB[b * HH + h] = red[0][th] + red[1][th] + red[2][th] + red[3][th];
  }
}

// ================= att_a: softmax_h(sim) @ hyp  (W k-contig, V transposed-staged) =================
__global__ __launch_bounds__(256, 3) void att_a_mfma(const float* __restrict__ sim,
                                                     const float* __restrict__ hyp,
                                                     const int* __restrict__ pmask,
                                                     const float* __restrict__ maxA,
                                                     const float* __restrict__ sumA,
                                                     float* __restrict__ out) {
  const int b = blockIdx.z;
  const int p0 = blockIdx.y * 128, d0 = blockIdx.x * 128;
  const float* S = sim + (size_t)b * PP * HH;
  const float* V = hyp + (size_t)b * HH * DD;

  __shared__ char sW[128 * 64], sV[128 * 64];

  const int t = threadIdx.x;
  const int lane = t & 63, wid = t >> 6;
  const int l15 = lane & 15, l4 = lane >> 4;
  const int wr = (wid >> 1) * 64, wc = (wid & 1) * 64;

  const int r = t >> 1, kh = t & 1;          // W staging (k-contiguous rows)
  const float cA = (pmask[b * PP + p0 + r] == 0) ? NEG_MASK : 0.f;
  const float mA = maxA[b * PP + p0 + r];

  const int m = t & 31, q = t >> 5;          // V 4x4-block transpose staging

  f32x4 acc[4][4] = {};

  for (int kk = 0; kk < HH; kk += 32) {
    f32x4 rs[4], rv[4];
#pragma unroll
    for (int c = 0; c < 4; ++c)
      rs[c] = *reinterpret_cast<const f32x4*>(S + (size_t)(p0 + r) * HH + kk + kh * 16 + c * 4);
#pragma unroll
    for (int jj = 0; jj < 4; ++jj)
      rv[jj] = *reinterpret_cast<const f32x4*>(V + (size_t)(kk + q * 4 + jj) * DD + d0 + m * 4);
    __syncthreads();
#pragma unroll
    for (int c = 0; c < 4; ++c) {
      bf4 w;
#pragma unroll
      for (int e = 0; e < 4; ++e)
        w[e] = (__bf16)__expf((rs[c][e] + cA) - mA);
      *reinterpret_cast<bf4*>(sW + swz(r, kh * 32 + c * 8)) = w;
    }
#pragma unroll
    for (int i = 0; i < 4; ++i) {            // d-column i of the 4x4 block
      bf4 v;
#pragma unroll
      for (int jj = 0; jj < 4; ++jj) v[jj] = (__bf16)rv[jj][i];
      *reinterpret_cast<bf4*>(sV + swz(m * 4 + i, q * 8)) = v;
    }
    __syncthreads();

    bfrag Wf[4], Vf[4];
#pragma unroll
    for (int i = 0; i < 4; ++i) {
      Wf[i] = *reinterpret_cast<const bfrag*>(sW + swz(wr + i * 16 + l15, l4 * 16));
      Vf[i] = *reinterpret_cast<const bfrag*>(sV + swz(wc + i * 16 + l15, l4 * 16));
    }
#pragma unroll
    for (int i = 0; i < 4; ++i)
#pragma unroll
      for (int j = 0; j < 4; ++j)
        acc[i][j] = MFMA(Wf[i], Vf[j], acc[i][j]);
  }

  float* O = out + (size_t)b * PP * DD;
#pragma unroll
  for (int i = 0; i < 4; ++i)
#pragma unroll
    for (int rr = 0; rr < 4; ++rr) {
      const int prow = p0 + wr + i * 16 + l4 * 4 + rr;
      const float inv = 1.f / sumA[b * PP + prow];
#pragma unroll
      for (int j = 0; j < 4; ++j)
        O[(size_t)prow * DD + d0 + wc + j * 16 + l15] = acc[i][j][rr] * inv;
    }
}

// ================= att_b: softmax_p(sim)^T @ pre  (both operands transposed-staged) =================
__global__ __launch_bounds__(256, 3) void att_b_mfma(const float* __restrict__ sim,
                                                     const float* __restrict__ pre,
                                                     const int* __restrict__ hmask,
                                                     const float* __restrict__ maxB,
                                                     const float* __restrict__ sumB,
                                                     float* __restrict__ out) {
  const int b = blockIdx.z;
  const int h0 = blockIdx.y * 128, d0 = blockIdx.x * 128;
  const float* S = sim + (size_t)b * PP * HH;
  const float* U = pre + (size_t)b * PP * DD;

  __shared__ char sW[128 * 64], sU[128 * 64];

  const int t = threadIdx.x;
  const int lane = t & 63, wid = t >> 6;
  const int l15 = lane & 15, l4 = lane >> 4;
  const int wr = (wid >> 1) * 64, wc = (wid & 1) * 64;

  const int m = t & 31, q = t >> 5;          // 4x4 blocks: rows m*4+i, k-cols q*4+jj

  float cH[4], mB[4];
#pragma unroll
  for (int i = 0; i < 4; ++i) {
    const int h = h0 + m * 4 + i;
    cH[i] = (hmask[b * HH + h] == 0) ? NEG_MASK : 0.f;
    mB[i] = maxB[b * HH + h];
  }

  f32x4 acc[4][4] = {};

  for (int kk = 0; kk < PP; kk += 32) {
    f32x4 rs[4], ru[4];
#pragma unroll
    for (int jj = 0; jj < 4; ++jj) {
      rs[jj] = *reinterpret_cast<const f32x4*>(S + (size_t)(kk + q * 4 + jj) * HH + h0 + m * 4);
      ru[jj] = *reinterpret_cast<const f32x4*>(U + (size_t)(kk + q * 4 + jj) * DD + d0 + m * 4);
    }
    __syncthreads();
#pragma unroll
    for (int i = 0; i < 4; ++i) {
      bf4 w, u;
#pragma unroll
      for (int jj = 0; jj < 4; ++jj) {
        w[jj] = (__bf16)__expf((rs[jj][i] + cH[i]) - mB[i]);
        u[jj] = (__bf16)ru[jj][i];
      }
      *reinterpret_cast<bf4*>(sW + swz(m * 4 + i, q * 8)) = w;
      *reinterpret_cast<bf4*>(sU + swz(m * 4 + i, q * 8)) = u;
    }
    __syncthreads();

    bfrag Wf[4], Uf[4];
#pragma unroll
    for (int i = 0; i < 4; ++i) {
      Wf[i] = *reinterpret_cast<const bfrag*>(sW + swz(wr + i * 16 + l15, l4 * 16));
      Uf[i] = *reinterpret_cast<const bfrag*>(sU + swz(wc + i * 16 + l15, l4 * 16));
    }
#pragma unroll
    for (int i = 0; i < 4; ++i)
#pragma unroll
      for (int j = 0; j < 4; ++j)
        acc[i][j] = MFMA(Wf[i], Uf[j], acc[i][j]);
  }

  float* O = out + (size_t)b * HH * DD;
#pragma unroll
  for (int i = 0; i < 4; ++i)
#pragma unroll
    for (int rr = 0; rr < 4; ++rr) {
      const int hrow = h0 + wr + i * 16 + l4 * 4 + rr;
      const float inv = 1.f / sumB[b * HH + hrow];
#pragma unroll
      for (int j = 0; j < 4; ++j)
        O[(size_t)hrow * DD + d0 + wc + j * 16 + l15] = acc[i][j][rr] * inv;
    }
}

extern "C" void kernel_launch(void* const* d_in, const int* in_sizes, int n_in,
                              void* d_out, int out_size, void* d_ws, size_t ws_size,
                              hipStream_t stream) {
  const float* pre  = (const float*)d_in[0];
  const int* pmask  = (const int*)d_in[1];
  const float* hyp  = (const float*)d_in[2];
  const int* hmask  = (const int*)d_in[3];

  float* out0 = (float*)d_out;                    // attended_premises   [B,P,D]
  float* out1 = out0 + (size_t)BB * PP * DD;      // attended_hypothesis [B,H,D]

  float* sim  = (float*)d_ws;                     // [B,P,H] f32
  float* maxA = sim + (size_t)BB * PP * HH;       // [B,P]
  float* sumA = maxA + BB * PP;
  float* maxB = sumA + BB * PP;                   // [B,H]
  float* sumB = maxB + BB * HH;

  sim_mfma<<<dim3(HH / 128, PP / 128, BB), 256, 0, stream>>>(pre, hyp, sim);
  stats_rows<<<dim3(BB * PP / 4), 256, 0, stream>>>(sim, pmask, maxA, sumA);
  stats_cols<<<dim3(HH / 64, BB), 256, 0, stream>>>(sim, hmask, maxB, sumB);
  att_a_mfma<<<dim3(DD / 128, PP / 128, BB), 256, 0, stream>>>(sim, hyp, pmask, maxA, sumA, out0);
  att_b_mfma<<<dim3(DD / 128, HH / 128, BB), 256, 0, stream>>>(sim, pre, hmask, maxB, sumB, out1);
}